// Round 6
// baseline (253.732 us; speedup 1.0000x reference)
//
#include <hip/hip_runtime.h>

// Butterworth order-4 lowpass = 2 cascaded biquads (Direct Form II), fp32.
// B*C = 256 signals, T = 96000. Chunked linear-recurrence decomposition:
//  K1: per (signal, chunk) zero-state pass -> final 4-state
//  K2: sequential-over-chunks state composition via A = M^CLEN (4x4)
//  K3: re-run each chunk with true initial state -> y
//
// R6 change: LDS-transposed window tiles in K1/K3. Global reads/writes are
// line-granular (16 lanes x 16B = 256B contiguous per segment); the per-lane
// 16B-stride-1536B pattern (64 scattered lines per instr, partial-line
// writes) is gone. Recurrence consumes/produces LDS rows (stride 65 floats
// -> bank (t+j)%32, 2-way aliasing = free). K3 computes y in place in the
// x tile: one 65000 B buffer, under the 64 KB static LDS limit.
#define NSIG   256
#define T_LEN  96000
#define NCHUNK 250
#define CLEN   384                  // T_LEN / NCHUNK
#define W      64                   // window samples per tile
#define NW     (CLEN / W)           // 6 windows
#define ROWF   (W + 1)              // padded LDS row stride (floats)
#define TILE_F4 (NCHUNK * (W / 4))  // 4000 float4 per window

struct Coefs {
  float b01, b11, b21, na11, na21;   // section 0: b/a0, -a1/a0, -a2/a0
  float b02, b12, b22, na12, na22;   // section 1
};

__device__ __forceinline__ Coefs load_coefs(const float* __restrict__ sos) {
  Coefs c;
  float i0 = 1.0f / sos[3];
  c.b01 = sos[0] * i0; c.b11 = sos[1] * i0; c.b21 = sos[2] * i0;
  c.na11 = -sos[4] * i0; c.na21 = -sos[5] * i0;
  float i1 = 1.0f / sos[9];
  c.b02 = sos[6] * i1; c.b12 = sos[7] * i1; c.b22 = sos[8] * i1;
  c.na12 = -sos[10] * i1; c.na22 = -sos[11] * i1;
  return c;
}

// One sample through both sections. State = (w11,w21,w12,w22).
__device__ __forceinline__ float step2(float xin, float& w11, float& w21,
                                       float& w12, float& w22, const Coefs& c) {
  float w0 = fmaf(c.na11, w11, fmaf(c.na21, w21, xin));
  float y1 = fmaf(c.b21, w21, fmaf(c.b11, w11, c.b01 * w0));
  w21 = w11; w11 = w0;
  float w0b = fmaf(c.na12, w12, fmaf(c.na22, w22, y1));
  float y2 = fmaf(c.b22, w22, fmaf(c.b12, w12, c.b02 * w0b));
  w22 = w12; w12 = w0b;
  return y2;
}

// K1: zero-state chunk pass; store final state only. Block = 1 signal.
__global__ __launch_bounds__(256) void k_phase1(const float* __restrict__ x,
                                                const float* __restrict__ sos,
                                                float4* __restrict__ vzs) {
  __shared__ float xs[NCHUNK * ROWF];   // 65000 B
  int sig = blockIdx.x, tid = threadIdx.x;
  Coefs cf = load_coefs(sos);
  const float4* xg = reinterpret_cast<const float4*>(x) + (size_t)sig * (T_LEN / 4);
  float w11 = 0.f, w21 = 0.f, w12 = 0.f, w22 = 0.f;
  for (int wi = 0; wi < NW; ++wi) {
    __syncthreads();                    // prev window fully consumed
    for (int u = tid; u < TILE_F4; u += 256) {
      int c = u >> 4, k4 = u & 15;      // 16 lanes per 256B segment
      float4 v = xg[c * (CLEN / 4) + wi * (W / 4) + k4];
      float* dst = &xs[c * ROWF + k4 * 4];
      dst[0] = v.x; dst[1] = v.y; dst[2] = v.z; dst[3] = v.w;
    }
    __syncthreads();
    if (tid < NCHUNK) {
      const float* xr = &xs[tid * ROWF];
#pragma unroll 8
      for (int j = 0; j < W; ++j)
        (void)step2(xr[j], w11, w21, w12, w22, cf);
    }
  }
  if (tid < NCHUNK) {
    float4 st; st.x = w11; st.y = w21; st.z = w12; st.w = w22;
    vzs[(size_t)tid * NSIG + sig] = st;
  }
}

// K2: one block. Lanes 0..3 build A = M^CLEN by evolving basis vectors with
// x=0; then each thread (= one signal) composes initial states across chunks
// with a 10-deep register-prefetch pipeline:
//   v_init[0] = 0;  v_init[c+1] = A * v_init[c] + v_zs[c]
#define PF 10   // NCHUNK = 25 groups * PF
__global__ __launch_bounds__(256) void k_scan(const float* __restrict__ sos,
                                              const float4* __restrict__ vzs,
                                              float4* __restrict__ vinit) {
  __shared__ float Ash[16];
  Coefs cf = load_coefs(sos);
  int t = threadIdx.x;
  if (t < 4) {
    float w11 = (t == 0) ? 1.f : 0.f;
    float w21 = (t == 1) ? 1.f : 0.f;
    float w12 = (t == 2) ? 1.f : 0.f;
    float w22 = (t == 3) ? 1.f : 0.f;
    for (int j = 0; j < CLEN; ++j)
      (void)step2(0.f, w11, w21, w12, w22, cf);
    Ash[0 * 4 + t] = w11; Ash[1 * 4 + t] = w21;   // column t of A
    Ash[2 * 4 + t] = w12; Ash[3 * 4 + t] = w22;
  }
  __syncthreads();
  float A[16];
#pragma unroll
  for (int i = 0; i < 16; ++i) A[i] = Ash[i];

  float4 zb[PF], zb2[PF];
#pragma unroll
  for (int i = 0; i < PF; ++i) zb[i] = vzs[(size_t)i * NSIG + t];
  float4 v; v.x = 0.f; v.y = 0.f; v.z = 0.f; v.w = 0.f;
  for (int g = 0; g < NCHUNK / PF; ++g) {
#pragma unroll
    for (int i = 0; i < PF; ++i) {
      int c2 = (g + 1) * PF + i;
      c2 = c2 < NCHUNK ? c2 : NCHUNK - 1;
      zb2[i] = vzs[(size_t)c2 * NSIG + t];
    }
#pragma unroll
    for (int i = 0; i < PF; ++i) {
      int c = g * PF + i;
      vinit[(size_t)c * NSIG + t] = v;             // state entering chunk c
      float4 z = zb[i];
      float4 nv;
      nv.x = fmaf(A[ 3], v.w, fmaf(A[ 2], v.z, fmaf(A[ 1], v.y, fmaf(A[ 0], v.x, z.x))));
      nv.y = fmaf(A[ 7], v.w, fmaf(A[ 6], v.z, fmaf(A[ 5], v.y, fmaf(A[ 4], v.x, z.y))));
      nv.z = fmaf(A[11], v.w, fmaf(A[10], v.z, fmaf(A[ 9], v.y, fmaf(A[ 8], v.x, z.z))));
      nv.w = fmaf(A[15], v.w, fmaf(A[14], v.z, fmaf(A[13], v.y, fmaf(A[12], v.x, z.w))));
      v = nv;
    }
#pragma unroll
    for (int i = 0; i < PF; ++i) zb[i] = zb2[i];
  }
}

// K3: re-run each chunk with the true initial state; y computed in place in
// the LDS tile, then stored line-granular.
__global__ __launch_bounds__(256) void k_phase3(const float* __restrict__ x,
                                                const float* __restrict__ sos,
                                                const float4* __restrict__ vinit,
                                                float* __restrict__ y) {
  __shared__ float ts[NCHUNK * ROWF];   // 65000 B, x then y in place
  int sig = blockIdx.x, tid = threadIdx.x;
  Coefs cf = load_coefs(sos);
  const float4* xg = reinterpret_cast<const float4*>(x) + (size_t)sig * (T_LEN / 4);
  float4* yg = reinterpret_cast<float4*>(y) + (size_t)sig * (T_LEN / 4);
  float w11 = 0.f, w21 = 0.f, w12 = 0.f, w22 = 0.f;
  if (tid < NCHUNK) {
    float4 v = vinit[(size_t)tid * NSIG + sig];
    w11 = v.x; w21 = v.y; w12 = v.z; w22 = v.w;
  }
  for (int wi = 0; wi < NW; ++wi) {
    __syncthreads();                    // prev window's stores done
    for (int u = tid; u < TILE_F4; u += 256) {
      int c = u >> 4, k4 = u & 15;
      float4 v = xg[c * (CLEN / 4) + wi * (W / 4) + k4];
      float* dst = &ts[c * ROWF + k4 * 4];
      dst[0] = v.x; dst[1] = v.y; dst[2] = v.z; dst[3] = v.w;
    }
    __syncthreads();
    if (tid < NCHUNK) {
      float* xr = &ts[tid * ROWF];
#pragma unroll 8
      for (int j = 0; j < W; ++j)
        xr[j] = step2(xr[j], w11, w21, w12, w22, cf);   // in-place y
    }
    __syncthreads();
    for (int u = tid; u < TILE_F4; u += 256) {
      int c = u >> 4, k4 = u & 15;
      const float* s = &ts[c * ROWF + k4 * 4];
      float4 v; v.x = s[0]; v.y = s[1]; v.z = s[2]; v.w = s[3];
      yg[c * (CLEN / 4) + wi * (W / 4) + k4] = v;
    }
  }
}

extern "C" void kernel_launch(void* const* d_in, const int* in_sizes, int n_in,
                              void* d_out, int out_size, void* d_ws, size_t ws_size,
                              hipStream_t stream) {
  const float* x   = (const float*)d_in[0];   // (32, 8, 96000) fp32
  const float* sos = (const float*)d_in[1];   // (2, 6) fp32
  float* yout = (float*)d_out;
  // ws layout: [vzs: NCHUNK*NSIG float4][vinit: NCHUNK*NSIG float4] = 2 MB
  float4* vzs   = (float4*)d_ws;
  float4* vinit = vzs + (size_t)NCHUNK * NSIG;

  k_phase1<<<NSIG, 256, 0, stream>>>(x, sos, vzs);
  k_scan<<<1, 256, 0, stream>>>(sos, vzs, vinit);
  k_phase3<<<NSIG, 256, 0, stream>>>(x, sos, vinit, yout);
}